// Round 6
// baseline (46.341 us; speedup 1.0000x reference)
//
#include <hip/hip_runtime.h>
#include <hip/hip_bf16.h>

// ---------------------------------------------------------------------------
// PointNet2 FP module, 2 launches:
//   knn_prep: blocks 0..43   -> W1t[256][448], W2t[256][256] bf16 (transposed)
//             blocks 44..    -> knn(k=3)+interp+concat -> H[16384][448] bf16
//   gemm12b:  per 64-row strip (512 thr, 8 waves): barrier-free register GEMM.
//             GEMM1 operands DIRECT from global (K-contiguous rows, immediate
//             offsets) -> h1 in LDS (one barrier) -> GEMM2 -> out fp32.
// Round-5 lesson: 25 barrier-phases x ~5k cy stall dominated (MfmaUtil 3.4%).
// This version has exactly ONE barrier in the GEMM kernel.
// ---------------------------------------------------------------------------

typedef __bf16 bf16x8 __attribute__((ext_vector_type(8)));
typedef float  f32x4  __attribute__((ext_vector_type(4)));

__device__ __forceinline__ unsigned short f2bf(float f) {
  __hip_bfloat16 h = __float2bfloat16(f);
  return __builtin_bit_cast(unsigned short, h);
}

static constexpr int MROWS = 16384;
static constexpr int KP1   = 448;   // 7 * 64  (387 real, zero-padded)
static constexpr int KREAL = 387;
static constexpr int NK1   = 7;     // 448 / 64
static constexpr int NK2   = 4;     // 256 / 64
static constexpr int H1STR = 264;   // h1 LDS row stride (shorts)

// ------------------- kernel A: weight prep + knn/interp/concat -------------
__global__ __launch_bounds__(256) void knn_prep(
    const float* __restrict__ in_x,      // [4096, 256]
    const float* __restrict__ in_pos,    // [4096, 3]
    const float* __restrict__ skip_x,    // [16384, 128]
    const float* __restrict__ skip_pos,  // [16384, 3]
    const float* __restrict__ W1, const float* __restrict__ W2,
    unsigned short* __restrict__ W1t, unsigned short* __restrict__ W2t,
    unsigned short* __restrict__ H)      // [16384, 448] bf16
{
  __shared__ float T[64][65];
  __shared__ float P[3][256];
  const int tid = threadIdx.x;

  if (blockIdx.x < 44) {   // ---------------- weight transpose+cast ----------
    int b = blockIdx.x;
    const float* S; unsigned short* D; int KP, Kreal, kb, nb;
    if (b < 28) { S = W1; D = W1t; KP = KP1; Kreal = KREAL; kb = b >> 2; nb = b & 3; }
    else { b -= 28; S = W2; D = W2t; KP = 256; Kreal = 256; kb = b >> 2; nb = b & 3; }
    const int k0 = kb << 6, n0 = nb << 6;
    const int tr = tid >> 4, tc = tid & 15;
#pragma unroll
    for (int i = 0; i < 4; ++i) {
      const int k = k0 + i * 16 + tr;
      float4 v = make_float4(0.f, 0.f, 0.f, 0.f);
      if (k < Kreal) v = *(const float4*)(S + (size_t)k * 256 + n0 + tc * 4);
      T[i * 16 + tr][tc * 4 + 0] = v.x;
      T[i * 16 + tr][tc * 4 + 1] = v.y;
      T[i * 16 + tr][tc * 4 + 2] = v.z;
      T[i * 16 + tr][tc * 4 + 3] = v.w;
    }
    __syncthreads();
#pragma unroll
    for (int i = 0; i < 4; ++i) {
      const int n = n0 + i * 16 + tr;
      const int k = k0 + tc * 4;
      if (k < KP) {
        ushort4 o;
        o.x = f2bf(T[tc * 4 + 0][i * 16 + tr]);
        o.y = f2bf(T[tc * 4 + 1][i * 16 + tr]);
        o.z = f2bf(T[tc * 4 + 2][i * 16 + tr]);
        o.w = f2bf(T[tc * 4 + 3][i * 16 + tr]);
        *(ushort4*)(D + (size_t)n * KP + k) = o;
      }
    }
    return;
  }

  // ---------------- knn(k=3) + interpolate + concat -> H ----------
  const int s0 = (blockIdx.x - 44) << 2;   // first skip point of block
  const int ib = (s0 >> 10) << 8;          // first in-point of batch
  {
    const float* bp = in_pos + (size_t)ib * 3;
    for (int i = tid; i < 768; i += 256) P[i % 3][i / 3] = bp[i];
  }
  __syncthreads();

  const int wid = tid >> 6, lane = tid & 63;
  const int s = s0 + wid;
  const float sx = skip_pos[(size_t)s * 3 + 0];
  const float sy = skip_pos[(size_t)s * 3 + 1];
  const float sz = skip_pos[(size_t)s * 3 + 2];

  float d2[4];
#pragma unroll
  for (int q = 0; q < 4; ++q) {   // numpy op-order, no fma contraction
    const int i = lane + (q << 6);
    const float dx = __fsub_rn(sx, P[0][i]);
    const float dy = __fsub_rn(sy, P[1][i]);
    const float dz = __fsub_rn(sz, P[2][i]);
    d2[q] = __fadd_rn(__fadd_rn(__fmul_rn(dx, dx), __fmul_rn(dy, dy)),
                      __fmul_rn(dz, dz));
  }

  int gsel[3]; float wsel[3]; float wsum = 0.f;
#pragma unroll
  for (int p = 0; p < 3; ++p) {
    float bd = d2[0]; int bi = lane;
#pragma unroll
    for (int q = 1; q < 4; ++q) {
      const int i = lane + (q << 6);
      if (d2[q] < bd) { bd = d2[q]; bi = i; }
    }
#pragma unroll
    for (int m = 1; m < 64; m <<= 1) {   // argmin butterfly, low-idx tiebreak
      const float od = __shfl_xor(bd, m);
      const int   oi = __shfl_xor(bi, m);
      if (od < bd || (od == bd && oi < bi)) { bd = od; bi = oi; }
    }
    const bool win = ((bi & 63) == lane);
    const int  qw  = bi >> 6;             // static-index removal (rule 20)
    d2[0] = (win && qw == 0) ? 3.4e38f : d2[0];
    d2[1] = (win && qw == 1) ? 3.4e38f : d2[1];
    d2[2] = (win && qw == 2) ? 3.4e38f : d2[2];
    d2[3] = (win && qw == 3) ? 3.4e38f : d2[3];
    gsel[p] = bi;
    const float w = 1.0f / fmaxf(sqrtf(bd), 1e-10f);
    wsel[p] = w; wsum += w;
  }
  const float denom = wsum + 1e-16f;
  const float w0 = wsel[0] / denom;
  const float w1 = wsel[1] / denom;
  const float w2 = wsel[2] / denom;

  const f32x4 a = *(const f32x4*)(in_x + (size_t)(ib + gsel[0]) * 256 + lane * 4);
  const f32x4 b = *(const f32x4*)(in_x + (size_t)(ib + gsel[1]) * 256 + lane * 4);
  const f32x4 c = *(const f32x4*)(in_x + (size_t)(ib + gsel[2]) * 256 + lane * 4);

  unsigned short* hr = H + (size_t)s * KP1;
  ushort4 o4;
  o4.x = f2bf(w0 * a.x + w1 * b.x + w2 * c.x);
  o4.y = f2bf(w0 * a.y + w1 * b.y + w2 * c.y);
  o4.z = f2bf(w0 * a.z + w1 * b.z + w2 * c.z);
  o4.w = f2bf(w0 * a.w + w1 * b.w + w2 * c.w);
  *(ushort4*)(hr + (lane << 2)) = o4;

  const float2 sv = ((const float2*)(skip_x + (size_t)s * 128))[lane];
  ushort2 o2; o2.x = f2bf(sv.x); o2.y = f2bf(sv.y);
  *(ushort2*)(hr + 256 + (lane << 1)) = o2;

  // cols 384..447: pos(3) + zero-pad (all 64 lanes)
  {
    const float v = (lane == 0) ? sx : (lane == 1) ? sy : (lane == 2) ? sz : 0.f;
    hr[384 + lane] = f2bf(v);
  }
}

// ------------------- kernel B: barrier-free register GEMM ------------------
// 256 blocks x 512 thr (8 waves). Block owns 64 rows; wave = 64 rows x 32 cols.
// Operands loaded straight from global (immediate offsets); ONE barrier total.
__global__ __launch_bounds__(512) void gemm12b(
    const unsigned short* __restrict__ Hg,   // [16384][448] bf16
    const unsigned short* __restrict__ W1t,  // [256][448]  bf16
    const unsigned short* __restrict__ W2t,  // [256][256]  bf16
    const float* __restrict__ bias1, const float* __restrict__ bias2,
    float* __restrict__ out)                 // [16384][256]
{
  __shared__ unsigned short h1s[64 * H1STR];   // 33,792 B

  const int tid = threadIdx.x, lane = tid & 63, wid = tid >> 6;
  const int m0 = blockIdx.x << 6;
  const int fr = lane & 15, g = lane >> 4;
  const int c0 = wid << 5;                     // wave cols [c0, c0+32)

  // base pointers: per-lane row bases, K-contiguous; K-step offsets immediate
  const unsigned short* ph[4];
  const unsigned short* pw[2];
#pragma unroll
  for (int j = 0; j < 4; ++j)
    ph[j] = Hg + (size_t)(m0 + j * 16 + fr) * KP1 + g * 8;
#pragma unroll
  for (int i = 0; i < 2; ++i)
    pw[i] = W1t + (size_t)(c0 + i * 16 + fr) * KP1 + g * 8;

  f32x4 acc[2][4] = {};   // [mc = col frag][rf = row frag]

  // ---- GEMM1: 7 x BK=64, pure register flow, no barriers ----
#pragma unroll
  for (int ks = 0; ks < NK1; ++ks) {
    bf16x8 wf[2][2], hf[4][2];
#pragma unroll
    for (int kk = 0; kk < 2; ++kk) {
#pragma unroll
      for (int i = 0; i < 2; ++i)
        wf[i][kk] = *(const bf16x8*)(pw[i] + ks * 64 + kk * 32);
#pragma unroll
      for (int j = 0; j < 4; ++j)
        hf[j][kk] = *(const bf16x8*)(ph[j] + ks * 64 + kk * 32);
    }
#pragma unroll
    for (int kk = 0; kk < 2; ++kk)
#pragma unroll
      for (int mc = 0; mc < 2; ++mc)
#pragma unroll
        for (int rf = 0; rf < 4; ++rf)
          acc[mc][rf] = __builtin_amdgcn_mfma_f32_16x16x32_bf16(
              wf[mc][kk], hf[rf][kk], acc[mc][rf], 0, 0, 0);
  }

  // ---- h1 = relu(acc + b1) -> LDS (bf16) ----
  f32x4 bv1[2];
#pragma unroll
  for (int mc = 0; mc < 2; ++mc)
    bv1[mc] = *(const f32x4*)(bias1 + c0 + mc * 16 + g * 4);
#pragma unroll
  for (int rf = 0; rf < 4; ++rf)
#pragma unroll
    for (int mc = 0; mc < 2; ++mc) {
      ushort4 o;
      o.x = f2bf(fmaxf(acc[mc][rf][0] + bv1[mc][0], 0.f));
      o.y = f2bf(fmaxf(acc[mc][rf][1] + bv1[mc][1], 0.f));
      o.z = f2bf(fmaxf(acc[mc][rf][2] + bv1[mc][2], 0.f));
      o.w = f2bf(fmaxf(acc[mc][rf][3] + bv1[mc][3], 0.f));
      *(ushort4*)&h1s[(rf * 16 + fr) * H1STR + c0 + mc * 16 + g * 4] = o;
    }
  __syncthreads();   // the ONE barrier: h1 strip visible to all waves

#pragma unroll
  for (int mc = 0; mc < 2; ++mc)
#pragma unroll
    for (int rf = 0; rf < 4; ++rf) acc[mc][rf] = f32x4{0.f, 0.f, 0.f, 0.f};

  // ---- GEMM2: 4 x BK=64, W2 from global, h1 from LDS, no barriers ----
  const unsigned short* pw2[2];
#pragma unroll
  for (int i = 0; i < 2; ++i)
    pw2[i] = W2t + (size_t)(c0 + i * 16 + fr) * 256 + g * 8;
  const int hbase[4] = {
      (0 * 16 + fr) * H1STR + g * 8, (1 * 16 + fr) * H1STR + g * 8,
      (2 * 16 + fr) * H1STR + g * 8, (3 * 16 + fr) * H1STR + g * 8};

#pragma unroll
  for (int ks = 0; ks < NK2; ++ks) {
    bf16x8 wf[2][2], hf[4][2];
#pragma unroll
    for (int kk = 0; kk < 2; ++kk) {
#pragma unroll
      for (int i = 0; i < 2; ++i)
        wf[i][kk] = *(const bf16x8*)(pw2[i] + ks * 64 + kk * 32);
#pragma unroll
      for (int j = 0; j < 4; ++j)
        hf[j][kk] = *(const bf16x8*)&h1s[hbase[j] + ks * 64 + kk * 32];
    }
#pragma unroll
    for (int kk = 0; kk < 2; ++kk)
#pragma unroll
      for (int mc = 0; mc < 2; ++mc)
#pragma unroll
        for (int rf = 0; rf < 4; ++rf)
          acc[mc][rf] = __builtin_amdgcn_mfma_f32_16x16x32_bf16(
              wf[mc][kk], hf[rf][kk], acc[mc][rf], 0, 0, 0);
  }

  // ---- out = relu(acc + b2), coalesced float4 stores ----
  f32x4 bv2[2];
#pragma unroll
  for (int mc = 0; mc < 2; ++mc)
    bv2[mc] = *(const f32x4*)(bias2 + c0 + mc * 16 + g * 4);
#pragma unroll
  for (int rf = 0; rf < 4; ++rf) {
    const size_t row = (size_t)(m0 + rf * 16 + fr);
#pragma unroll
    for (int mc = 0; mc < 2; ++mc) {
      f32x4 o;
#pragma unroll
      for (int j = 0; j < 4; ++j) o[j] = fmaxf(acc[mc][rf][j] + bv2[mc][j], 0.f);
      *(f32x4*)(out + row * 256 + c0 + mc * 16 + g * 4) = o;
    }
  }
}

// ---------------------------------------------------------------------------
extern "C" void kernel_launch(void* const* d_in, const int* in_sizes, int n_in,
                              void* d_out, int out_size, void* d_ws, size_t ws_size,
                              hipStream_t stream) {
  const float* in_x     = (const float*)d_in[0];
  const float* in_pos   = (const float*)d_in[1];
  const float* skip_x   = (const float*)d_in[3];
  const float* skip_pos = (const float*)d_in[4];
  const float* W1       = (const float*)d_in[6];
  const float* bias1    = (const float*)d_in[7];
  const float* W2       = (const float*)d_in[8];
  const float* bias2    = (const float*)d_in[9];

  char* ws = (char*)d_ws;
  unsigned short* W1t = (unsigned short*)(ws);                    // 229,376 B
  unsigned short* W2t = (unsigned short*)(ws + 229376);           // 131,072 B
  unsigned short* H   = (unsigned short*)(ws + 229376 + 131072);  // 14,680,064 B

  knn_prep<<<dim3(44 + MROWS / 4), dim3(256), 0, stream>>>(
      in_x, in_pos, skip_x, skip_pos, W1, W2, W1t, W2t, H);
  gemm12b<<<dim3(MROWS / 64), dim3(512), 0, stream>>>(
      H, W1t, W2t, bias1, bias2, (float*)d_out);
}

// Round 7
// 41.137 us; speedup vs baseline: 1.1265x; 1.1265x over previous
//
#include <hip/hip_runtime.h>
#include <hip/hip_bf16.h>

// ---------------------------------------------------------------------------
// PointNet2 FP module, 2 launches (round-4 champion + BK=64 + knn16):
//   knn_prep: blocks 0..43  -> W1t[256][448], W2t[256][256] bf16 (transposed)
//             blocks 44..   -> knn(k=3)+interp+concat -> H[16384][448] bf16
//             (16 points/block, 4/wave with interleaved argmin butterflies)
//   gemm12d:  per 64-row strip (256 thr, 4 waves): h1 = relu(H@W1+b1) in LDS,
//             out = relu(h1@W2+b2). BK=64 (two 32-k halves, proven R4 layout),
//             2-buffer counted-vmcnt pipeline, XOR-swizzle both-sides.
// ---------------------------------------------------------------------------

typedef __bf16 bf16x8 __attribute__((ext_vector_type(8)));
typedef float  f32x4  __attribute__((ext_vector_type(4)));

__device__ __forceinline__ unsigned short f2bf(float f) {
  __hip_bfloat16 h = __float2bfloat16(f);
  return __builtin_bit_cast(unsigned short, h);
}

#define GLDS16(G, L)                                                          \
  __builtin_amdgcn_global_load_lds(                                           \
      (const __attribute__((address_space(1))) void*)(G),                     \
      (__attribute__((address_space(3))) void*)(L), 16, 0, 0)

#define BAR()    __builtin_amdgcn_s_barrier()
#define WAITV(N) asm volatile("s_waitcnt vmcnt(" #N ")" ::: "memory")
#define WAITL()  asm volatile("s_waitcnt lgkmcnt(0)" ::: "memory")

static constexpr int MROWS = 16384;
static constexpr int KP1   = 448;   // 7 * 64  (387 real, zero-padded)
static constexpr int KREAL = 387;
static constexpr int NK1   = 7;     // 448 / 64
static constexpr int NK2   = 4;     // 256 / 64
static constexpr int H1STR = 264;   // h1 LDS row stride (shorts)

// ------------------- kernel A: weight prep + knn/interp/concat -------------
__global__ __launch_bounds__(256) void knn_prep(
    const float* __restrict__ in_x,      // [4096, 256]
    const float* __restrict__ in_pos,    // [4096, 3]
    const float* __restrict__ skip_x,    // [16384, 128]
    const float* __restrict__ skip_pos,  // [16384, 3]
    const float* __restrict__ W1, const float* __restrict__ W2,
    unsigned short* __restrict__ W1t, unsigned short* __restrict__ W2t,
    unsigned short* __restrict__ H)      // [16384, 448] bf16
{
  __shared__ float T[64][65];
  __shared__ float P[3][256];
  const int tid = threadIdx.x;

  if (blockIdx.x < 44) {   // ---------------- weight transpose+cast ----------
    int b = blockIdx.x;
    const float* S; unsigned short* D; int KP, Kreal, kb, nb;
    if (b < 28) { S = W1; D = W1t; KP = KP1; Kreal = KREAL; kb = b >> 2; nb = b & 3; }
    else { b -= 28; S = W2; D = W2t; KP = 256; Kreal = 256; kb = b >> 2; nb = b & 3; }
    const int k0 = kb << 6, n0 = nb << 6;
    const int tr = tid >> 4, tc = tid & 15;
#pragma unroll
    for (int i = 0; i < 4; ++i) {
      const int k = k0 + i * 16 + tr;
      float4 v = make_float4(0.f, 0.f, 0.f, 0.f);
      if (k < Kreal) v = *(const float4*)(S + (size_t)k * 256 + n0 + tc * 4);
      T[i * 16 + tr][tc * 4 + 0] = v.x;
      T[i * 16 + tr][tc * 4 + 1] = v.y;
      T[i * 16 + tr][tc * 4 + 2] = v.z;
      T[i * 16 + tr][tc * 4 + 3] = v.w;
    }
    __syncthreads();
#pragma unroll
    for (int i = 0; i < 4; ++i) {
      const int n = n0 + i * 16 + tr;
      const int k = k0 + tc * 4;
      if (k < KP) {
        ushort4 o;
        o.x = f2bf(T[tc * 4 + 0][i * 16 + tr]);
        o.y = f2bf(T[tc * 4 + 1][i * 16 + tr]);
        o.z = f2bf(T[tc * 4 + 2][i * 16 + tr]);
        o.w = f2bf(T[tc * 4 + 3][i * 16 + tr]);
        *(ushort4*)(D + (size_t)n * KP + k) = o;
      }
    }
    return;
  }

  // ---------------- knn(k=3) + interpolate + concat -> H ----------
  // 16 skip points/block, 4 per wave, 4-way interleaved (R5-verified numerics)
  const int s0 = (blockIdx.x - 44) << 4;   // first skip point of block
  const int ib = (s0 >> 10) << 8;          // first in-point of batch
  {
    const float* bp = in_pos + (size_t)ib * 3;
    for (int i = tid; i < 768; i += 256) P[i % 3][i / 3] = bp[i];
  }
  __syncthreads();

  const int wid = tid >> 6, lane = tid & 63;
  const int sw = s0 + wid * 4;             // wave's first point

  float Pxr[4], Pyr[4], Pzr[4];
#pragma unroll
  for (int q = 0; q < 4; ++q) {
    Pxr[q] = P[0][lane + q * 64];
    Pyr[q] = P[1][lane + q * 64];
    Pzr[q] = P[2][lane + q * 64];
  }
  float spv = 0.f;
  if (lane < 12) spv = skip_pos[(size_t)sw * 3 + lane];

  float sx[4], sy[4], sz[4], d2[4][4];
#pragma unroll
  for (int u = 0; u < 4; ++u) {
    sx[u] = __shfl(spv, 3 * u + 0);
    sy[u] = __shfl(spv, 3 * u + 1);
    sz[u] = __shfl(spv, 3 * u + 2);
#pragma unroll
    for (int q = 0; q < 4; ++q) {   // numpy op-order, no fma contraction
      const float dx = __fsub_rn(sx[u], Pxr[q]);
      const float dy = __fsub_rn(sy[u], Pyr[q]);
      const float dz = __fsub_rn(sz[u], Pzr[q]);
      d2[u][q] = __fadd_rn(__fadd_rn(__fmul_rn(dx, dx), __fmul_rn(dy, dy)),
                           __fmul_rn(dz, dz));
    }
  }
  int gsel[4][3]; float wsel[4][3], wsum[4] = {0.f, 0.f, 0.f, 0.f};
#pragma unroll
  for (int p = 0; p < 3; ++p) {
    float bd[4]; int bi[4];
#pragma unroll
    for (int u = 0; u < 4; ++u) {
      bd[u] = d2[u][0]; bi[u] = lane;
#pragma unroll
      for (int q = 1; q < 4; ++q)
        if (d2[u][q] < bd[u]) { bd[u] = d2[u][q]; bi[u] = lane + (q << 6); }
    }
#pragma unroll
    for (int mk = 1; mk < 64; mk <<= 1) {   // 4 interleaved argmin butterflies
#pragma unroll
      for (int u = 0; u < 4; ++u) {
        const float od = __shfl_xor(bd[u], mk);
        const int   oi = __shfl_xor(bi[u], mk);
        if (od < bd[u] || (od == bd[u] && oi < bi[u])) { bd[u] = od; bi[u] = oi; }
      }
    }
#pragma unroll
    for (int u = 0; u < 4; ++u) {
      const bool win = ((bi[u] & 63) == lane);
      const int  qw  = bi[u] >> 6;          // static-index removal (rule 20)
      d2[u][0] = (win && qw == 0) ? 3.4e38f : d2[u][0];
      d2[u][1] = (win && qw == 1) ? 3.4e38f : d2[u][1];
      d2[u][2] = (win && qw == 2) ? 3.4e38f : d2[u][2];
      d2[u][3] = (win && qw == 3) ? 3.4e38f : d2[u][3];
      gsel[u][p] = bi[u];
      const float w = 1.0f / fmaxf(sqrtf(bd[u]), 1e-10f);
      wsel[u][p] = w; wsum[u] += w;
    }
  }
#pragma unroll
  for (int u = 0; u < 4; ++u) {
    const int s = sw + u;
    const float denom = wsum[u] + 1e-16f;
    const float w0 = wsel[u][0] / denom;
    const float w1 = wsel[u][1] / denom;
    const float w2 = wsel[u][2] / denom;
    const f32x4 a = *(const f32x4*)(in_x + (size_t)(ib + gsel[u][0]) * 256 + lane * 4);
    const f32x4 b = *(const f32x4*)(in_x + (size_t)(ib + gsel[u][1]) * 256 + lane * 4);
    const f32x4 c = *(const f32x4*)(in_x + (size_t)(ib + gsel[u][2]) * 256 + lane * 4);
    unsigned short* hr = H + (size_t)s * KP1;
    ushort4 o4;
    o4.x = f2bf(w0 * a.x + w1 * b.x + w2 * c.x);
    o4.y = f2bf(w0 * a.y + w1 * b.y + w2 * c.y);
    o4.z = f2bf(w0 * a.z + w1 * b.z + w2 * c.z);
    o4.w = f2bf(w0 * a.w + w1 * b.w + w2 * c.w);
    *(ushort4*)(hr + (lane << 2)) = o4;
    const float2 sv = ((const float2*)(skip_x + (size_t)s * 128))[lane];
    ushort2 o2; o2.x = f2bf(sv.x); o2.y = f2bf(sv.y);
    *(ushort2*)(hr + 256 + (lane << 1)) = o2;
    // cols 384..447: pos(3) + zero-pad (all 64 lanes)
    const float v = (lane == 0) ? sx[u] : (lane == 1) ? sy[u]
                  : (lane == 2) ? sz[u] : 0.f;
    hr[384 + lane] = f2bf(v);
  }
}

// ------------------- kernel B: fused GEMM1 -> LDS h1 -> GEMM2 --------------
// 256 blocks x 256 thr (4 waves); block owns rows m0..m0+63, all 256 cols.
// BK=64 as two proven 32-k halves; 11 MFMA phases total (was 21).
__global__ __launch_bounds__(256) void gemm12d(
    const unsigned short* __restrict__ Hg,   // [16384][448] bf16
    const unsigned short* __restrict__ W1t,  // [256][448]  bf16
    const unsigned short* __restrict__ W2t,  // [256][256]  bf16
    const float* __restrict__ bias1, const float* __restrict__ bias2,
    float* __restrict__ out)                 // [16384][256]
{
  __shared__ unsigned short As[2][2][64 * 32];    // 16 KiB (H k-halves)
  __shared__ unsigned short Bs[2][2][256 * 32];   // 64 KiB (W k-halves)
  __shared__ unsigned short h1s[64 * H1STR];      // 33 KiB

  const int tid = threadIdx.x, lane = tid & 63, wid = tid >> 6;
  const int m0 = blockIdx.x << 6;
  const int fr = lane & 15, g = lane >> 4;
  const int wcc = wid << 6;                       // wave's 64-col band

  // stage source addressing: thread t -> row t/4, chunk (t%4) XOR row-swizzle
  const int r  = tid >> 2;                        // 0..63
  const int cs = (tid & 3) ^ ((r >> 1) & 3);
  const unsigned short* gA  = Hg  + (size_t)(m0 + r) * KP1 + cs * 8;
  const unsigned short* gB1 = W1t + (size_t)r * KP1 + cs * 8;
  const unsigned short* gB2 = W2t + (size_t)r * 256 + cs * 8;

#define STG1(ks, bu)                                                          \
  {                                                                           \
    _Pragma("unroll")                                                         \
    for (int kk_ = 0; kk_ < 2; ++kk_) {                                       \
      const int _ko = (ks) * 64 + kk_ * 32;                                   \
      GLDS16(gA + _ko, &As[bu][kk_][wid * 512]);                              \
      GLDS16(gB1 + _ko,              &Bs[bu][kk_][wid * 512]);                \
      GLDS16(gB1 + 64 * KP1 + _ko,   &Bs[bu][kk_][2048 + wid * 512]);         \
      GLDS16(gB1 + 128 * KP1 + _ko,  &Bs[bu][kk_][4096 + wid * 512]);         \
      GLDS16(gB1 + 192 * KP1 + _ko,  &Bs[bu][kk_][6144 + wid * 512]);         \
    }                                                                         \
  }
#define STG2(ks, bu)                                                          \
  {                                                                           \
    _Pragma("unroll")                                                         \
    for (int kk_ = 0; kk_ < 2; ++kk_) {                                       \
      const int _ko = (ks) * 64 + kk_ * 32;                                   \
      GLDS16(gB2 + _ko,              &Bs[bu][kk_][wid * 512]);                \
      GLDS16(gB2 + 64 * 256 + _ko,   &Bs[bu][kk_][2048 + wid * 512]);         \
      GLDS16(gB2 + 128 * 256 + _ko,  &Bs[bu][kk_][4096 + wid * 512]);         \
      GLDS16(gB2 + 192 * 256 + _ko,  &Bs[bu][kk_][6144 + wid * 512]);         \
    }                                                                         \
  }

  STG1(0, 0); STG1(1, 1);   // prologue: 20 loads in flight

  // fragment read offsets (XOR read side matches pre-swizzled source)
  int woff[4], hoff[4], h2off[4];
#pragma unroll
  for (int i = 0; i < 4; ++i) {
    const int Rw = wcc + i * 16 + fr;          // W row (0..255) = output col
    const int Rh = i * 16 + fr;                // H row (0..63)  = output row
    woff[i]  = Rw * 32 + ((g ^ ((Rw >> 1) & 3)) << 3);
    hoff[i]  = Rh * 32 + ((g ^ ((Rh >> 1) & 3)) << 3);
    h2off[i] = Rh * H1STR + g * 8;             // padded stride, no swizzle
  }

  f32x4 bv1[4], bv2[4];
#pragma unroll
  for (int mc = 0; mc < 4; ++mc) {
    bv1[mc] = *(const f32x4*)(bias1 + wcc + mc * 16 + g * 4);
    bv2[mc] = *(const f32x4*)(bias2 + wcc + mc * 16 + g * 4);
  }

  f32x4 acc[4][4] = {};   // [mc = col frag][rr = row frag]

  // ---- GEMM1: 7 phases of BK=64 (10 loads/stage) ----
#pragma unroll 1
  for (int ks = 0; ks < NK1; ++ks) {
    if (ks < NK1 - 1) { WAITV(10); } else { WAITV(0); }
    BAR();
    bf16x8 wf[4][2], hf[4][2];
#pragma unroll
    for (int kk = 0; kk < 2; ++kk) {
#pragma unroll
      for (int i = 0; i < 4; ++i) {
        wf[i][kk] = *(const bf16x8*)&Bs[ks & 1][kk][woff[i]];
        hf[i][kk] = *(const bf16x8*)&As[ks & 1][kk][hoff[i]];
      }
    }
#pragma unroll
    for (int kk = 0; kk < 2; ++kk)
#pragma unroll
      for (int mc = 0; mc < 4; ++mc)
#pragma unroll
        for (int rr = 0; rr < 4; ++rr)
          acc[mc][rr] = __builtin_amdgcn_mfma_f32_16x16x32_bf16(
              wf[mc][kk], hf[rr][kk], acc[mc][rr], 0, 0, 0);
    WAITL(); BAR();   // all waves done with buf before restage
    if (ks + 2 < NK1) STG1(ks + 2, ks & 1);
  }

  // GEMM2 prologue staging — latency hides under h1 epilogue
  STG2(0, 0); STG2(1, 1);

  // h1 epilogue: bias+relu+bf16 -> LDS strip (lane owns rows rr*16+fr)
#pragma unroll
  for (int rr = 0; rr < 4; ++rr)
#pragma unroll
    for (int mc = 0; mc < 4; ++mc) {
      ushort4 o;
      o.x = f2bf(fmaxf(acc[mc][rr][0] + bv1[mc][0], 0.f));
      o.y = f2bf(fmaxf(acc[mc][rr][1] + bv1[mc][1], 0.f));
      o.z = f2bf(fmaxf(acc[mc][rr][2] + bv1[mc][2], 0.f));
      o.w = f2bf(fmaxf(acc[mc][rr][3] + bv1[mc][3], 0.f));
      *(ushort4*)&h1s[(rr * 16 + fr) * H1STR + wcc + mc * 16 + g * 4] = o;
    }
  WAITL(); BAR();   // h1 strip visible to all waves

#pragma unroll
  for (int mc = 0; mc < 4; ++mc)
#pragma unroll
    for (int rr = 0; rr < 4; ++rr) acc[mc][rr] = f32x4{0.f, 0.f, 0.f, 0.f};

  // ---- GEMM2: 4 phases of BK=64, A from LDS h1s (8 loads/stage) ----
#pragma unroll 1
  for (int ks = 0; ks < NK2; ++ks) {
    if (ks < NK2 - 1) { WAITV(8); } else { WAITV(0); }
    BAR();
    bf16x8 wf[4][2], hf[4][2];
#pragma unroll
    for (int kk = 0; kk < 2; ++kk) {
#pragma unroll
      for (int i = 0; i < 4; ++i) {
        wf[i][kk] = *(const bf16x8*)&Bs[ks & 1][kk][woff[i]];
        hf[i][kk] = *(const bf16x8*)&h1s[h2off[i] + ks * 64 + kk * 32];
      }
    }
#pragma unroll
    for (int kk = 0; kk < 2; ++kk)
#pragma unroll
      for (int mc = 0; mc < 4; ++mc)
#pragma unroll
        for (int rr = 0; rr < 4; ++rr)
          acc[mc][rr] = __builtin_amdgcn_mfma_f32_16x16x32_bf16(
              wf[mc][kk], hf[rr][kk], acc[mc][rr], 0, 0, 0);
    WAITL(); BAR();
    if (ks + 2 < NK2) STG2(ks + 2, ks & 1);
  }
#undef STG1
#undef STG2

  // final epilogue: coalesced float4 stores
#pragma unroll
  for (int rr = 0; rr < 4; ++rr) {
    const size_t row = (size_t)(m0 + rr * 16 + fr);
#pragma unroll
    for (int mc = 0; mc < 4; ++mc) {
      f32x4 o;
#pragma unroll
      for (int j = 0; j < 4; ++j) o[j] = fmaxf(acc[mc][rr][j] + bv2[mc][j], 0.f);
      *(f32x4*)(out + row * 256 + wcc + mc * 16 + g * 4) = o;
    }
  }
}

// ---------------------------------------------------------------------------
extern "C" void kernel_launch(void* const* d_in, const int* in_sizes, int n_in,
                              void* d_out, int out_size, void* d_ws, size_t ws_size,
                              hipStream_t stream) {
  const float* in_x     = (const float*)d_in[0];
  const float* in_pos   = (const float*)d_in[1];
  const float* skip_x   = (const float*)d_in[3];
  const float* skip_pos = (const float*)d_in[4];
  const float* W1       = (const float*)d_in[6];
  const float* bias1    = (const float*)d_in[7];
  const float* W2       = (const float*)d_in[8];
  const float* bias2    = (const float*)d_in[9];

  char* ws = (char*)d_ws;
  unsigned short* W1t = (unsigned short*)(ws);                    // 229,376 B
  unsigned short* W2t = (unsigned short*)(ws + 229376);           // 131,072 B
  unsigned short* H   = (unsigned short*)(ws + 229376 + 131072);  // 14,680,064 B

  knn_prep<<<dim3(44 + MROWS / 16), dim3(256), 0, stream>>>(
      in_x, in_pos, skip_x, skip_pos, W1, W2, W1t, W2t, H);
  gemm12d<<<dim3(MROWS / 64), dim3(256), 0, stream>>>(
      H, W1t, W2t, bias1, bias2, (float*)d_out);
}